// Round 1
// baseline (2420.630 us; speedup 1.0000x reference)
//
#include <hip/hip_runtime.h>
#include <math.h>

// ---------------- constants ----------------
#define SQ   256          // tokens
#define DD   2048         // model dim
#define NHD  16           // heads
#define DHD  128          // head dim
#define MLPD 8192
#define KIN  4096         // INPUT_D
#define INV_SQRT_DH 0.08838834764831845f

__device__ __forceinline__ float gelu_f(float x) {
    return 0.5f * x * (1.0f + erff(x * 0.70710678118654752f));
}

// ---------------- generic 256xN GEMM: C = op(A @ W + bias) ----------------
// MODE 0: += positional embedding (patch embed)
// MODE 1: gelu
// MODE 2: residual add into C
template<int MODE>
__global__ __launch_bounds__(256) void gemm_k(const float* __restrict__ A,
                                              const float* __restrict__ W,
                                              const float* __restrict__ bias,
                                              float* __restrict__ C,
                                              int M, int N, int K) {
    __shared__ float As[32][65];
    __shared__ float Ws[32][65];
    const int bn = blockIdx.x, bm = blockIdx.y;
    const int tid = threadIdx.x;
    const int tx = tid & 15, ty = tid >> 4;
    const int m0 = bm * 64, n0 = bn * 64;
    float acc[4][4] = {};
    for (int k0 = 0; k0 < K; k0 += 32) {
        #pragma unroll
        for (int i = tid; i < 64 * 32; i += 256) {
            int m = i >> 5, kk = i & 31;
            As[kk][m] = A[(m0 + m) * K + k0 + kk];
        }
        #pragma unroll
        for (int i = tid; i < 32 * 64; i += 256) {
            int kk = i >> 6, n = i & 63;
            Ws[kk][n] = W[(k0 + kk) * N + n0 + n];
        }
        __syncthreads();
        #pragma unroll
        for (int kk = 0; kk < 32; ++kk) {
            float a[4], b[4];
            #pragma unroll
            for (int i = 0; i < 4; i++) a[i] = As[kk][ty * 4 + i];
            #pragma unroll
            for (int j = 0; j < 4; j++) b[j] = Ws[kk][tx * 4 + j];
            #pragma unroll
            for (int i = 0; i < 4; i++)
                #pragma unroll
                for (int j = 0; j < 4; j++) acc[i][j] += a[i] * b[j];
        }
        __syncthreads();
    }
    #pragma unroll
    for (int i = 0; i < 4; i++) {
        int m = m0 + ty * 4 + i;
        #pragma unroll
        for (int j = 0; j < 4; j++) {
            int n = n0 + tx * 4 + j;
            float val = acc[i][j] + bias[n];
            if (MODE == 0) {
                float jf = (float)n;
                float expo = ((n & 1) ? (jf - 1.0f) : jf) * (1.0f / 2048.0f);
                float ang = (float)m * powf(10000.0f, -expo);
                val += (n & 1) ? cosf(ang) : sinf(ang);
                C[m * N + n] = val;
            } else if (MODE == 1) {
                C[m * N + n] = gelu_f(val);
            } else {
                C[m * N + n] += val;
            }
        }
    }
}

// ---------------- layernorm (one block per row); optionally zero a buffer ----------------
__global__ __launch_bounds__(256) void ln_kernel(const float* __restrict__ xin,
                                                 const float* __restrict__ g,
                                                 const float* __restrict__ b,
                                                 float* __restrict__ out,
                                                 float* __restrict__ zbuf, int zn) {
    __shared__ float red[8];
    const int tid = threadIdx.x;
    for (int i = tid; i < zn; i += 256) zbuf[i] = 0.0f;
    const int row = blockIdx.x;
    const float* xr = xin + row * DD;
    float vals[8];
    float s = 0.0f;
    #pragma unroll
    for (int i = 0; i < 8; i++) { vals[i] = xr[tid + i * 256]; s += vals[i]; }
    #pragma unroll
    for (int o = 32; o > 0; o >>= 1) s += __shfl_down(s, o);
    if ((tid & 63) == 0) red[tid >> 6] = s;
    __syncthreads();
    if (tid == 0) red[4] = (red[0] + red[1] + red[2] + red[3]) * (1.0f / 2048.0f);
    __syncthreads();
    const float mean = red[4];
    float vs = 0.0f;
    #pragma unroll
    for (int i = 0; i < 8; i++) { float d = vals[i] - mean; vs += d * d; }
    #pragma unroll
    for (int o = 32; o > 0; o >>= 1) vs += __shfl_down(vs, o);
    if ((tid & 63) == 0) red[tid >> 6] = vs;
    __syncthreads();
    if (tid == 0) red[5] = rsqrtf((red[0] + red[1] + red[2] + red[3]) * (1.0f / 2048.0f) + 1e-5f);
    __syncthreads();
    const float inv = red[5];
    #pragma unroll
    for (int i = 0; i < 8; i++) {
        int c = tid + i * 256;
        out[row * DD + c] = (vals[i] - mean) * inv * g[c] + b[c];
    }
}

// ---------------- per-head QKV projection ----------------
// grid: (head, m-tile of 64, type q/k/v)
__global__ __launch_bounds__(256) void qkv_kernel(const float* __restrict__ h,
                                                  const float* __restrict__ qw, const float* __restrict__ kw,
                                                  const float* __restrict__ vw, const float* __restrict__ qb,
                                                  const float* __restrict__ kb, const float* __restrict__ vb,
                                                  float* __restrict__ q, float* __restrict__ k,
                                                  float* __restrict__ v) {
    __shared__ float As[32][65];
    __shared__ float Ws[32][132];
    const int head = blockIdx.x;
    const int m0 = blockIdx.y * 64;
    const int type = blockIdx.z;
    const float* W; const float* B; float* O;
    if (type == 0)      { W = qw; B = qb; O = q; }
    else if (type == 1) { W = kw; B = kb; O = k; }
    else                { W = vw; B = vb; O = v; }
    W += head * DHD * DHD;
    B += head * DHD;
    const int tid = threadIdx.x;
    const int tx = tid & 15, ty = tid >> 4;
    float acc[4][8] = {};
    for (int k0 = 0; k0 < DHD; k0 += 32) {
        #pragma unroll
        for (int i = tid; i < 64 * 32; i += 256) {
            int m = i >> 5, kk = i & 31;
            As[kk][m] = h[(m0 + m) * DD + head * DHD + k0 + kk];
        }
        #pragma unroll
        for (int i = tid; i < 32 * 128; i += 256) {
            int kk = i >> 7, n = i & 127;
            Ws[kk][n] = W[(k0 + kk) * DHD + n];
        }
        __syncthreads();
        #pragma unroll
        for (int kk = 0; kk < 32; ++kk) {
            float a[4], bb[8];
            #pragma unroll
            for (int i = 0; i < 4; i++) a[i] = As[kk][ty * 4 + i];
            #pragma unroll
            for (int j = 0; j < 8; j++) bb[j] = Ws[kk][tx * 8 + j];
            #pragma unroll
            for (int i = 0; i < 4; i++)
                #pragma unroll
                for (int j = 0; j < 8; j++) acc[i][j] += a[i] * bb[j];
        }
        __syncthreads();
    }
    #pragma unroll
    for (int i = 0; i < 4; i++) {
        int s = m0 + ty * 4 + i;
        #pragma unroll
        for (int j = 0; j < 8; j++) {
            int e = tx * 8 + j;
            O[s * DD + head * DHD + e] = acc[i][j] + B[e];
        }
    }
}

// ---------------- full attention (block 1): x += softmax(qk^T/s) v ----------------
// grid: (16 heads, 16 chunks of 16 query rows)
__global__ __launch_bounds__(256) void attn_kernel(const float* __restrict__ q,
                                                   const float* __restrict__ k,
                                                   const float* __restrict__ v,
                                                   float* __restrict__ x) {
    __shared__ float qs[16][129];
    __shared__ float ks[32][129];
    __shared__ float ps[16][257];
    const int head = blockIdx.x, r0 = blockIdx.y * 16;
    const int tid = threadIdx.x, hoff = head * DHD;
    for (int i = tid; i < 16 * 128; i += 256) {
        int r = i >> 7, d = i & 127;
        qs[r][d] = q[(r0 + r) * DD + hoff + d];
    }
    for (int jt = 0; jt < 256; jt += 32) {
        __syncthreads();
        for (int i = tid; i < 32 * 128; i += 256) {
            int r = i >> 7, d = i & 127;
            ks[r][d] = k[(jt + r) * DD + hoff + d];
        }
        __syncthreads();
        #pragma unroll
        for (int idx = tid; idx < 16 * 32; idx += 256) {
            int i = idx >> 5, j = idx & 31;
            float s = 0.0f;
            #pragma unroll
            for (int d = 0; d < 128; d++) s += qs[i][d] * ks[j][d];
            ps[i][jt + j] = s * INV_SQRT_DH;
        }
    }
    __syncthreads();
    if (tid < 16) {
        float mx = -1e30f;
        for (int j = 0; j < 256; j++) mx = fmaxf(mx, ps[tid][j]);
        float sm = 0.0f;
        for (int j = 0; j < 256; j++) { float e = __expf(ps[tid][j] - mx); ps[tid][j] = e; sm += e; }
        float inv = 1.0f / sm;
        for (int j = 0; j < 256; j++) ps[tid][j] *= inv;
    }
    __syncthreads();
    for (int idx = tid; idx < 16 * 128; idx += 256) {
        int i = idx >> 7, e = idx & 127;
        float acc = 0.0f;
        #pragma unroll 8
        for (int j = 0; j < 256; j++) acc += ps[i][j] * v[j * DD + hoff + e];
        x[(r0 + i) * DD + hoff + e] += acc;
    }
}

// ---------------- block-2 attention, query row 0 only ----------------
__global__ __launch_bounds__(256) void attn0_kernel(const float* __restrict__ q,
                                                    const float* __restrict__ k,
                                                    const float* __restrict__ v,
                                                    float* __restrict__ x) {
    __shared__ float q0[128];
    __shared__ float p[256];
    __shared__ float red[8];
    const int h = blockIdx.x, tid = threadIdx.x, hoff = h * DHD;
    if (tid < 128) q0[tid] = q[hoff + tid];
    __syncthreads();
    const float* kr = k + tid * DD + hoff;
    float s = 0.0f;
    #pragma unroll 8
    for (int d = 0; d < 128; d++) s += q0[d] * kr[d];
    s *= INV_SQRT_DH;
    float m = s;
    #pragma unroll
    for (int o = 32; o > 0; o >>= 1) m = fmaxf(m, __shfl_down(m, o));
    if ((tid & 63) == 0) red[tid >> 6] = m;
    __syncthreads();
    if (tid == 0) red[4] = fmaxf(fmaxf(red[0], red[1]), fmaxf(red[2], red[3]));
    __syncthreads();
    const float mx = red[4];
    float e = __expf(s - mx);
    p[tid] = e;
    float t = e;
    #pragma unroll
    for (int o = 32; o > 0; o >>= 1) t += __shfl_down(t, o);
    if ((tid & 63) == 0) red[tid >> 6] = t;
    __syncthreads();
    if (tid == 0) red[5] = red[0] + red[1] + red[2] + red[3];
    __syncthreads();
    const float inv = 1.0f / red[5];
    if (tid < 128) {
        float acc = 0.0f;
        #pragma unroll 8
        for (int j = 0; j < 256; j++) acc += p[j] * v[j * DD + hoff + tid];
        x[hoff + tid] += acc * inv;
    }
}

// ---------------- block-2 MLP GEMVs (token 0 only) ----------------
__global__ __launch_bounds__(256) void gemv1_kernel(const float* __restrict__ h2,
                                                    const float* __restrict__ w1,
                                                    float* __restrict__ y) {
    const int n = blockIdx.x * 256 + threadIdx.x;
    const int k0 = blockIdx.y * 256;
    float s = 0.0f;
    #pragma unroll 8
    for (int k = 0; k < 256; k++) s += h2[k0 + k] * w1[(size_t)(k0 + k) * MLPD + n];
    atomicAdd(&y[n], s);
}

__global__ __launch_bounds__(256) void gelu_bias_kernel(float* __restrict__ y,
                                                        const float* __restrict__ b1) {
    const int n = blockIdx.x * 256 + threadIdx.x;
    y[n] = gelu_f(y[n] + b1[n]);
}

__global__ __launch_bounds__(256) void gemv2_kernel(const float* __restrict__ y1,
                                                    const float* __restrict__ w2,
                                                    float* __restrict__ x) {
    const int m = blockIdx.x * 256 + threadIdx.x;
    const int k0 = blockIdx.y * 512;
    float s = 0.0f;
    #pragma unroll 8
    for (int k = 0; k < 512; k++) s += y1[k0 + k] * w2[(size_t)(k0 + k) * DD + m];
    atomicAdd(&x[m], s);
}

// ---------------- head: sigmoid(cls . head_w + head_b), copy memory ----------------
__global__ __launch_bounds__(256) void head_kernel(const float* __restrict__ x,
                                                   const float* __restrict__ b2l,
                                                   const float* __restrict__ hw,
                                                   const float* __restrict__ hb,
                                                   const float* __restrict__ mem,
                                                   float* __restrict__ out) {
    __shared__ float red[8];
    const int tid = threadIdx.x;
    float s = 0.0f;
    for (int m = tid; m < 2048; m += 256) s += (x[m] + b2l[m]) * hw[m];
    #pragma unroll
    for (int o = 32; o > 0; o >>= 1) s += __shfl_down(s, o);
    if ((tid & 63) == 0) red[tid >> 6] = s;
    __syncthreads();
    if (tid == 0) {
        float t = red[0] + red[1] + red[2] + red[3];
        out[0] = 1.0f / (1.0f + __expf(-(t + hb[0])));
    }
    if (tid < 8) out[1 + tid] = mem[tid];
}

extern "C" void kernel_launch(void* const* d_in, const int* in_sizes, int n_in,
                              void* d_out, int out_size, void* d_ws, size_t ws_size,
                              hipStream_t stream) {
    const float* images = (const float*)d_in[0];
    const float* memory = (const float*)d_in[1];
    const float* wmap   = (const float*)d_in[2];
    const float* bmap   = (const float*)d_in[3];
    const float* ln1_g  = (const float*)d_in[4];
    const float* ln1_b  = (const float*)d_in[5];
    const float* qw     = (const float*)d_in[6];
    const float* qb     = (const float*)d_in[7];
    const float* kw     = (const float*)d_in[8];
    const float* kb     = (const float*)d_in[9];
    const float* vw     = (const float*)d_in[10];
    const float* vb     = (const float*)d_in[11];
    const float* ln2_g  = (const float*)d_in[12];
    const float* ln2_b  = (const float*)d_in[13];
    const float* w1     = (const float*)d_in[14];
    const float* b1     = (const float*)d_in[15];
    const float* w2     = (const float*)d_in[16];
    const float* b2     = (const float*)d_in[17];
    const float* head_w = (const float*)d_in[18];
    const float* head_b = (const float*)d_in[19];
    float* out = (float*)d_out;

    float* ws = (float*)d_ws;
    float* x     = ws;                    // 256*2048
    float* h     = x + SQ * DD;           // 256*2048
    float* q     = h + SQ * DD;           // 256*2048
    float* k     = q + SQ * DD;
    float* v     = k + SQ * DD;
    float* y1    = v + SQ * DD;           // 256*8192
    float* y1row = y1 + SQ * MLPD;        // 8192
    float* h2row = y1row + MLPD;          // 2048

    // patch embed + bias + positional embedding
    gemm_k<0><<<dim3(DD / 64, SQ / 64), 256, 0, stream>>>(images, wmap, bmap, x, SQ, DD, KIN);

    for (int l = 0; l < 2; l++) {
        const size_t wofs = (size_t)l * NHD * DHD * DHD;
        const size_t bofs = (size_t)l * NHD * DHD;
        ln_kernel<<<SQ, 256, 0, stream>>>(x, ln1_g + l * DD, ln1_b + l * DD, h, nullptr, 0);
        qkv_kernel<<<dim3(NHD, SQ / 64, 3), 256, 0, stream>>>(h, qw + wofs, kw + wofs, vw + wofs,
                                                              qb + bofs, kb + bofs, vb + bofs,
                                                              q, k, v);
        if (l == 0) {
            attn_kernel<<<dim3(NHD, SQ / 16), 256, 0, stream>>>(q, k, v, x);
            ln_kernel<<<SQ, 256, 0, stream>>>(x, ln2_g, ln2_b, h, nullptr, 0);
            gemm_k<1><<<dim3(MLPD / 64, SQ / 64), 256, 0, stream>>>(h, w1, b1, y1, SQ, MLPD, DD);
            gemm_k<2><<<dim3(DD / 64, SQ / 64), 256, 0, stream>>>(y1, w2, b2, x, SQ, DD, MLPD);
        } else {
            attn0_kernel<<<NHD, 256, 0, stream>>>(q, k, v, x);
            // LN2 of row 0 only; also zero y1row for gemv accumulation
            ln_kernel<<<1, 256, 0, stream>>>(x, ln2_g + DD, ln2_b + DD, h2row, y1row, MLPD);
            gemv1_kernel<<<dim3(MLPD / 256, 8), 256, 0, stream>>>(h2row, w1 + (size_t)DD * MLPD, y1row);
            gelu_bias_kernel<<<MLPD / 256, 256, 0, stream>>>(y1row, b1 + MLPD);
            gemv2_kernel<<<dim3(DD / 256, 16), 256, 0, stream>>>(y1row, w2 + (size_t)DD * MLPD, x);
            head_kernel<<<1, 256, 0, stream>>>(x, b2 + DD, head_w, head_b, memory, out);
        }
    }
}

// Round 2
// 1027.774 us; speedup vs baseline: 2.3552x; 2.3552x over previous
//
#include <hip/hip_runtime.h>
#include <math.h>

// ---------------- constants ----------------
#define SQ   256          // tokens
#define DD   2048         // model dim
#define NHD  16           // heads
#define DHD  128          // head dim
#define MLPD 8192
#define KIN  4096         // INPUT_D
#define INV_SQRT_DH 0.08838834764831845f

typedef __attribute__((ext_vector_type(8))) short bf16x8;
typedef __attribute__((ext_vector_type(4))) float f32x4;

__device__ __forceinline__ float gelu_f(float x) {
    return 0.5f * x * (1.0f + erff(x * 0.70710678118654752f));
}

// float -> bf16 round-to-nearest-even
__device__ __forceinline__ short f2bf(float f) {
    unsigned u = __float_as_uint(f);
    unsigned r = (u + 0x7fffu + ((u >> 16) & 1u)) >> 16;
    return (short)r;
}

// ---------------- bf16 MFMA GEMM: C = op(A @ W + bias) ----------------
// A fp32 [M][K] row-major, W fp32 [K][N] row-major; converted to bf16 in staging.
// Tile 64m x 64n, 256 threads = 4 waves, each wave a 16x64 strip.
// MODE 0: += positional embedding (patch embed)   MODE 1: gelu   MODE 2: residual +=
template<int MODE>
__global__ __launch_bounds__(256) void gemm_bf16(const float* __restrict__ A,
                                                 const float* __restrict__ W,
                                                 const float* __restrict__ bias,
                                                 float* __restrict__ C,
                                                 int M, int N, int K) {
    // rows padded to 40 bf16 (80B, 16B-aligned) -> frag ds_read_b128 ~2-way banks (free)
    __shared__ short As[64][40];   // [m][k] bf16
    __shared__ short Bs[64][40];   // [n][k] bf16 (W transposed)
    const int tid = threadIdx.x;
    const int n0 = blockIdx.x * 64, m0 = blockIdx.y * 64;
    const int wv = tid >> 6, ln = tid & 63;
    const int l15 = ln & 15, q = ln >> 4;

    f32x4 acc[4];
    #pragma unroll
    for (int j = 0; j < 4; j++) acc[j] = (f32x4){0.f, 0.f, 0.f, 0.f};

    const int am = tid >> 2, ak = (tid & 3) * 8;   // A staging coords
    const int bn = tid & 63, bk = (tid >> 6) * 8;  // B staging coords

    for (int k0 = 0; k0 < K; k0 += 32) {
        // stage A tile 64x32: 8 floats/thread (2x float4), convert, b128 LDS store
        {
            const float* ap = A + (size_t)(m0 + am) * K + k0 + ak;
            float4 a0 = *(const float4*)ap;
            float4 a1 = *(const float4*)(ap + 4);
            short t[8] = {f2bf(a0.x), f2bf(a0.y), f2bf(a0.z), f2bf(a0.w),
                          f2bf(a1.x), f2bf(a1.y), f2bf(a1.z), f2bf(a1.w)};
            *(bf16x8*)&As[am][ak] = *(bf16x8*)t;
        }
        // stage B tile 32x64 transposed -> Bs[n][k]: 8 strided rows, coalesced across lanes
        {
            const float* wp = W + (size_t)(k0 + bk) * N + n0 + bn;
            short t[8];
            #pragma unroll
            for (int j = 0; j < 8; j++) t[j] = f2bf(wp[(size_t)j * N]);
            *(bf16x8*)&Bs[bn][bk] = *(bf16x8*)t;
        }
        __syncthreads();
        // A-frag: [m=lane&15][k=(lane>>4)*8+j]; B-frag: [n=lane&15][k=...]
        bf16x8 af = *(bf16x8*)&As[16 * wv + l15][q * 8];
        #pragma unroll
        for (int j = 0; j < 4; j++) {
            bf16x8 bfr = *(bf16x8*)&Bs[16 * j + l15][q * 8];
            acc[j] = __builtin_amdgcn_mfma_f32_16x16x32_bf16(af, bfr, acc[j], 0, 0, 0);
        }
        __syncthreads();
    }
    // epilogue: D layout col=lane&15, row=(lane>>4)*4+reg  [m89]
    #pragma unroll
    for (int j = 0; j < 4; j++) {
        const int n = n0 + 16 * j + l15;
        #pragma unroll
        for (int i = 0; i < 4; i++) {
            const int m = m0 + 16 * wv + q * 4 + i;
            float val = acc[j][i] + bias[n];
            if (MODE == 0) {
                float jf = (float)n;
                float expo = ((n & 1) ? (jf - 1.0f) : jf) * (1.0f / 2048.0f);
                float ang = (float)m * powf(10000.0f, -expo);
                val += (n & 1) ? cosf(ang) : sinf(ang);
                C[(size_t)m * N + n] = val;
            } else if (MODE == 1) {
                C[(size_t)m * N + n] = gelu_f(val);
            } else {
                C[(size_t)m * N + n] += val;
            }
        }
    }
}

// ---------------- layernorm (one block per row); optionally zero a buffer ----------------
__global__ __launch_bounds__(256) void ln_kernel(const float* __restrict__ xin,
                                                 const float* __restrict__ g,
                                                 const float* __restrict__ b,
                                                 float* __restrict__ out,
                                                 float* __restrict__ zbuf, int zn) {
    __shared__ float red[8];
    const int tid = threadIdx.x;
    for (int i = tid; i < zn; i += 256) zbuf[i] = 0.0f;
    const int row = blockIdx.x;
    const float* xr = xin + row * DD;
    float vals[8];
    float s = 0.0f;
    #pragma unroll
    for (int i = 0; i < 8; i++) { vals[i] = xr[tid + i * 256]; s += vals[i]; }
    #pragma unroll
    for (int o = 32; o > 0; o >>= 1) s += __shfl_down(s, o);
    if ((tid & 63) == 0) red[tid >> 6] = s;
    __syncthreads();
    if (tid == 0) red[4] = (red[0] + red[1] + red[2] + red[3]) * (1.0f / 2048.0f);
    __syncthreads();
    const float mean = red[4];
    float vs = 0.0f;
    #pragma unroll
    for (int i = 0; i < 8; i++) { float d = vals[i] - mean; vs += d * d; }
    #pragma unroll
    for (int o = 32; o > 0; o >>= 1) vs += __shfl_down(vs, o);
    if ((tid & 63) == 0) red[tid >> 6] = vs;
    __syncthreads();
    if (tid == 0) red[5] = rsqrtf((red[0] + red[1] + red[2] + red[3]) * (1.0f / 2048.0f) + 1e-5f);
    __syncthreads();
    const float inv = red[5];
    #pragma unroll
    for (int i = 0; i < 8; i++) {
        int c = tid + i * 256;
        out[row * DD + c] = (vals[i] - mean) * inv * g[c] + b[c];
    }
}

// ---------------- per-head QKV projection ----------------
// grid: (head, m-tile of 64, type q/k/v)
__global__ __launch_bounds__(256) void qkv_kernel(const float* __restrict__ h,
                                                  const float* __restrict__ qw, const float* __restrict__ kw,
                                                  const float* __restrict__ vw, const float* __restrict__ qb,
                                                  const float* __restrict__ kb, const float* __restrict__ vb,
                                                  float* __restrict__ q, float* __restrict__ k,
                                                  float* __restrict__ v) {
    __shared__ float As[32][65];
    __shared__ float Ws[32][132];
    const int head = blockIdx.x;
    const int m0 = blockIdx.y * 64;
    const int type = blockIdx.z;
    const float* W; const float* B; float* O;
    if (type == 0)      { W = qw; B = qb; O = q; }
    else if (type == 1) { W = kw; B = kb; O = k; }
    else                { W = vw; B = vb; O = v; }
    W += head * DHD * DHD;
    B += head * DHD;
    const int tid = threadIdx.x;
    const int tx = tid & 15, ty = tid >> 4;
    float acc[4][8] = {};
    for (int k0 = 0; k0 < DHD; k0 += 32) {
        #pragma unroll
        for (int i = tid; i < 64 * 32; i += 256) {
            int m = i >> 5, kk = i & 31;
            As[kk][m] = h[(m0 + m) * DD + head * DHD + k0 + kk];
        }
        #pragma unroll
        for (int i = tid; i < 32 * 128; i += 256) {
            int kk = i >> 7, n = i & 127;
            Ws[kk][n] = W[(k0 + kk) * DHD + n];
        }
        __syncthreads();
        #pragma unroll
        for (int kk = 0; kk < 32; ++kk) {
            float a[4], bb[8];
            #pragma unroll
            for (int i = 0; i < 4; i++) a[i] = As[kk][ty * 4 + i];
            #pragma unroll
            for (int j = 0; j < 8; j++) bb[j] = Ws[kk][tx * 8 + j];
            #pragma unroll
            for (int i = 0; i < 4; i++)
                #pragma unroll
                for (int j = 0; j < 8; j++) acc[i][j] += a[i] * bb[j];
        }
        __syncthreads();
    }
    #pragma unroll
    for (int i = 0; i < 4; i++) {
        int s = m0 + ty * 4 + i;
        #pragma unroll
        for (int j = 0; j < 8; j++) {
            int e = tx * 8 + j;
            O[s * DD + head * DHD + e] = acc[i][j] + B[e];
        }
    }
}

// ---------------- full attention (block 1): x += softmax(qk^T/s) v ----------------
__global__ __launch_bounds__(256) void attn_kernel(const float* __restrict__ q,
                                                   const float* __restrict__ k,
                                                   const float* __restrict__ v,
                                                   float* __restrict__ x) {
    __shared__ float qs[16][129];
    __shared__ float ks[32][129];
    __shared__ float ps[16][257];
    const int head = blockIdx.x, r0 = blockIdx.y * 16;
    const int tid = threadIdx.x, hoff = head * DHD;
    for (int i = tid; i < 16 * 128; i += 256) {
        int r = i >> 7, d = i & 127;
        qs[r][d] = q[(r0 + r) * DD + hoff + d];
    }
    for (int jt = 0; jt < 256; jt += 32) {
        __syncthreads();
        for (int i = tid; i < 32 * 128; i += 256) {
            int r = i >> 7, d = i & 127;
            ks[r][d] = k[(jt + r) * DD + hoff + d];
        }
        __syncthreads();
        #pragma unroll
        for (int idx = tid; idx < 16 * 32; idx += 256) {
            int i = idx >> 5, j = idx & 31;
            float s = 0.0f;
            #pragma unroll
            for (int d = 0; d < 128; d++) s += qs[i][d] * ks[j][d];
            ps[i][jt + j] = s * INV_SQRT_DH;
        }
    }
    __syncthreads();
    if (tid < 16) {
        float mx = -1e30f;
        for (int j = 0; j < 256; j++) mx = fmaxf(mx, ps[tid][j]);
        float sm = 0.0f;
        for (int j = 0; j < 256; j++) { float e = __expf(ps[tid][j] - mx); ps[tid][j] = e; sm += e; }
        float inv = 1.0f / sm;
        for (int j = 0; j < 256; j++) ps[tid][j] *= inv;
    }
    __syncthreads();
    for (int idx = tid; idx < 16 * 128; idx += 256) {
        int i = idx >> 7, e = idx & 127;
        float acc = 0.0f;
        #pragma unroll 8
        for (int j = 0; j < 256; j++) acc += ps[i][j] * v[j * DD + hoff + e];
        x[(r0 + i) * DD + hoff + e] += acc;
    }
}

// ---------------- block-2 attention, query row 0 only ----------------
__global__ __launch_bounds__(256) void attn0_kernel(const float* __restrict__ q,
                                                    const float* __restrict__ k,
                                                    const float* __restrict__ v,
                                                    float* __restrict__ x) {
    __shared__ float q0[128];
    __shared__ float p[256];
    __shared__ float red[8];
    const int h = blockIdx.x, tid = threadIdx.x, hoff = h * DHD;
    if (tid < 128) q0[tid] = q[hoff + tid];
    __syncthreads();
    const float* kr = k + tid * DD + hoff;
    float s = 0.0f;
    #pragma unroll 8
    for (int d = 0; d < 128; d++) s += q0[d] * kr[d];
    s *= INV_SQRT_DH;
    float m = s;
    #pragma unroll
    for (int o = 32; o > 0; o >>= 1) m = fmaxf(m, __shfl_down(m, o));
    if ((tid & 63) == 0) red[tid >> 6] = m;
    __syncthreads();
    if (tid == 0) red[4] = fmaxf(fmaxf(red[0], red[1]), fmaxf(red[2], red[3]));
    __syncthreads();
    const float mx = red[4];
    float e = __expf(s - mx);
    p[tid] = e;
    float t = e;
    #pragma unroll
    for (int o = 32; o > 0; o >>= 1) t += __shfl_down(t, o);
    if ((tid & 63) == 0) red[tid >> 6] = t;
    __syncthreads();
    if (tid == 0) red[5] = red[0] + red[1] + red[2] + red[3];
    __syncthreads();
    const float inv = 1.0f / red[5];
    if (tid < 128) {
        float acc = 0.0f;
        #pragma unroll 8
        for (int j = 0; j < 256; j++) acc += p[j] * v[j * DD + hoff + tid];
        x[hoff + tid] += acc * inv;
    }
}

// ---------------- block-2 MLP GEMVs (token 0 only) ----------------
__global__ __launch_bounds__(256) void gemv1_kernel(const float* __restrict__ h2,
                                                    const float* __restrict__ w1,
                                                    float* __restrict__ y) {
    const int n = blockIdx.x * 256 + threadIdx.x;
    const int k0 = blockIdx.y * 256;
    float s = 0.0f;
    #pragma unroll 8
    for (int k = 0; k < 256; k++) s += h2[k0 + k] * w1[(size_t)(k0 + k) * MLPD + n];
    atomicAdd(&y[n], s);
}

__global__ __launch_bounds__(256) void gelu_bias_kernel(float* __restrict__ y,
                                                        const float* __restrict__ b1) {
    const int n = blockIdx.x * 256 + threadIdx.x;
    y[n] = gelu_f(y[n] + b1[n]);
}

__global__ __launch_bounds__(256) void gemv2_kernel(const float* __restrict__ y1,
                                                    const float* __restrict__ w2,
                                                    float* __restrict__ x) {
    const int m = blockIdx.x * 256 + threadIdx.x;
    const int k0 = blockIdx.y * 512;
    float s = 0.0f;
    #pragma unroll 8
    for (int k = 0; k < 512; k++) s += y1[k0 + k] * w2[(size_t)(k0 + k) * DD + m];
    atomicAdd(&x[m], s);
}

// ---------------- head: sigmoid(cls . head_w + head_b), copy memory ----------------
__global__ __launch_bounds__(256) void head_kernel(const float* __restrict__ x,
                                                   const float* __restrict__ b2l,
                                                   const float* __restrict__ hw,
                                                   const float* __restrict__ hb,
                                                   const float* __restrict__ mem,
                                                   float* __restrict__ out) {
    __shared__ float red[8];
    const int tid = threadIdx.x;
    float s = 0.0f;
    for (int m = tid; m < 2048; m += 256) s += (x[m] + b2l[m]) * hw[m];
    #pragma unroll
    for (int o = 32; o > 0; o >>= 1) s += __shfl_down(s, o);
    if ((tid & 63) == 0) red[tid >> 6] = s;
    __syncthreads();
    if (tid == 0) {
        float t = red[0] + red[1] + red[2] + red[3];
        out[0] = 1.0f / (1.0f + __expf(-(t + hb[0])));
    }
    if (tid < 8) out[1 + tid] = mem[tid];
}

extern "C" void kernel_launch(void* const* d_in, const int* in_sizes, int n_in,
                              void* d_out, int out_size, void* d_ws, size_t ws_size,
                              hipStream_t stream) {
    const float* images = (const float*)d_in[0];
    const float* memory = (const float*)d_in[1];
    const float* wmap   = (const float*)d_in[2];
    const float* bmap   = (const float*)d_in[3];
    const float* ln1_g  = (const float*)d_in[4];
    const float* ln1_b  = (const float*)d_in[5];
    const float* qw     = (const float*)d_in[6];
    const float* qb     = (const float*)d_in[7];
    const float* kw     = (const float*)d_in[8];
    const float* kb     = (const float*)d_in[9];
    const float* vw     = (const float*)d_in[10];
    const float* vb     = (const float*)d_in[11];
    const float* ln2_g  = (const float*)d_in[12];
    const float* ln2_b  = (const float*)d_in[13];
    const float* w1     = (const float*)d_in[14];
    const float* b1     = (const float*)d_in[15];
    const float* w2     = (const float*)d_in[16];
    const float* b2     = (const float*)d_in[17];
    const float* head_w = (const float*)d_in[18];
    const float* head_b = (const float*)d_in[19];
    float* out = (float*)d_out;

    float* ws = (float*)d_ws;
    float* x     = ws;                    // 256*2048
    float* h     = x + SQ * DD;           // 256*2048
    float* q     = h + SQ * DD;           // 256*2048
    float* k     = q + SQ * DD;
    float* v     = k + SQ * DD;
    float* y1    = v + SQ * DD;           // 256*8192
    float* y1row = y1 + SQ * MLPD;        // 8192
    float* h2row = y1row + MLPD;          // 2048

    // patch embed + bias + positional embedding (bf16 MFMA)
    gemm_bf16<0><<<dim3(DD / 64, SQ / 64), 256, 0, stream>>>(images, wmap, bmap, x, SQ, DD, KIN);

    for (int l = 0; l < 2; l++) {
        const size_t wofs = (size_t)l * NHD * DHD * DHD;
        const size_t bofs = (size_t)l * NHD * DHD;
        ln_kernel<<<SQ, 256, 0, stream>>>(x, ln1_g + l * DD, ln1_b + l * DD, h, nullptr, 0);
        qkv_kernel<<<dim3(NHD, SQ / 64, 3), 256, 0, stream>>>(h, qw + wofs, kw + wofs, vw + wofs,
                                                              qb + bofs, kb + bofs, vb + bofs,
                                                              q, k, v);
        if (l == 0) {
            attn_kernel<<<dim3(NHD, SQ / 16), 256, 0, stream>>>(q, k, v, x);
            ln_kernel<<<SQ, 256, 0, stream>>>(x, ln2_g, ln2_b, h, nullptr, 0);
            gemm_bf16<1><<<dim3(MLPD / 64, SQ / 64), 256, 0, stream>>>(h, w1, b1, y1, SQ, MLPD, DD);
            gemm_bf16<2><<<dim3(DD / 64, SQ / 64), 256, 0, stream>>>(y1, w2, b2, x, SQ, DD, MLPD);
        } else {
            attn0_kernel<<<NHD, 256, 0, stream>>>(q, k, v, x);
            // LN2 of row 0 only; also zero y1row for gemv accumulation
            ln_kernel<<<1, 256, 0, stream>>>(x, ln2_g + DD, ln2_b + DD, h2row, y1row, MLPD);
            gemv1_kernel<<<dim3(MLPD / 256, 8), 256, 0, stream>>>(h2row, w1 + (size_t)DD * MLPD, y1row);
            gelu_bias_kernel<<<MLPD / 256, 256, 0, stream>>>(y1row, b1 + MLPD);
            gemv2_kernel<<<dim3(DD / 256, 16), 256, 0, stream>>>(y1row, w2 + (size_t)DD * MLPD, x);
            head_kernel<<<1, 256, 0, stream>>>(x, b2 + DD, head_w, head_b, memory, out);
        }
    }
}

// Round 3
// 616.122 us; speedup vs baseline: 3.9288x; 1.6681x over previous
//
#include <hip/hip_runtime.h>
#include <math.h>

// ---------------- constants ----------------
#define SQ   256          // tokens
#define DD   2048         // model dim
#define NHD  16           // heads
#define DHD  128          // head dim
#define MLPD 8192
#define KIN  4096         // INPUT_D
#define INV_SQRT_DH 0.08838834764831845f

typedef __attribute__((ext_vector_type(8))) short bf16x8;
typedef __attribute__((ext_vector_type(4))) float f32x4;

__device__ __forceinline__ float gelu_f(float x) {
    return 0.5f * x * (1.0f + erff(x * 0.70710678118654752f));
}

// float -> bf16 round-to-nearest-even
__device__ __forceinline__ short f2bf(float f) {
    unsigned u = __float_as_uint(f);
    unsigned r = (u + 0x7fffu + ((u >> 16) & 1u)) >> 16;
    return (short)r;
}

// =====================================================================
// Split-K bf16 MFMA GEMM partial: atomicAdd(C, A[64m x KC] @ W[KC x 64n])
// A fp32 [M][K] rm, W fp32 [K][N] rm. Tile 64x64, Kstep 64, 4 waves.
// LDS: stride-64 rows + chunk-XOR swizzle (chunk ^= row&7) -> 0 excess
// bank conflicts on both stage-stores and frag-reads (verified on paper).
// =====================================================================
__global__ __launch_bounds__(256) void gemm_splitk(const float* __restrict__ A,
                                                   const float* __restrict__ W,
                                                   float* __restrict__ C,
                                                   int N, int K, int KC) {
    __shared__ short As[64 * 64];
    __shared__ short Bs[64 * 64];
    const int tid = threadIdx.x;
    const int n0 = blockIdx.x * 64, m0 = blockIdx.y * 64;
    const int kstart = blockIdx.z * KC;
    const int wv = tid >> 6, ln = tid & 63;
    const int l15 = ln & 15, q = ln >> 4;

    f32x4 acc[4];
    #pragma unroll
    for (int j = 0; j < 4; j++) acc[j] = (f32x4){0.f, 0.f, 0.f, 0.f};

    // staging coords
    const int am = tid >> 2, akb = (tid & 3) * 16, ac0 = (tid & 3) * 2;
    const int bn = tid & 63, bkb = (tid >> 6) * 16, bc0 = (tid >> 6) * 2;
    short* as0 = &As[am * 64 + ((ac0 ^ (am & 7)) * 8)];
    short* as1 = &As[am * 64 + (((ac0 + 1) ^ (am & 7)) * 8)];
    short* bs0 = &Bs[bn * 64 + ((bc0 ^ (bn & 7)) * 8)];
    short* bs1 = &Bs[bn * 64 + (((bc0 + 1) ^ (bn & 7)) * 8)];
    // fragment read addresses (A row fixed per lane)
    const int arow = 16 * wv + l15;
    const short* af0 = &As[arow * 64 + ((q ^ (arow & 7)) * 8)];
    const short* af1 = &As[arow * 64 + (((q + 4) ^ (arow & 7)) * 8)];

    for (int kc = kstart; kc < kstart + KC; kc += 64) {
        // issue global loads first (overlap with barrier wait)
        const float* ap = A + (size_t)(m0 + am) * K + kc + akb;
        float4 a0 = *(const float4*)ap;
        float4 a1 = *(const float4*)(ap + 4);
        float4 a2 = *(const float4*)(ap + 8);
        float4 a3 = *(const float4*)(ap + 12);
        const float* wp = W + (size_t)(kc + bkb) * N + n0 + bn;
        float wb[16];
        #pragma unroll
        for (int j = 0; j < 16; j++) wb[j] = wp[(size_t)j * N];

        __syncthreads();   // previous tile fully consumed
        {
            short t[16] = {f2bf(a0.x), f2bf(a0.y), f2bf(a0.z), f2bf(a0.w),
                           f2bf(a1.x), f2bf(a1.y), f2bf(a1.z), f2bf(a1.w),
                           f2bf(a2.x), f2bf(a2.y), f2bf(a2.z), f2bf(a2.w),
                           f2bf(a3.x), f2bf(a3.y), f2bf(a3.z), f2bf(a3.w)};
            *(bf16x8*)as0 = *(bf16x8*)&t[0];
            *(bf16x8*)as1 = *(bf16x8*)&t[8];
            short u[16];
            #pragma unroll
            for (int j = 0; j < 16; j++) u[j] = f2bf(wb[j]);
            *(bf16x8*)bs0 = *(bf16x8*)&u[0];
            *(bf16x8*)bs1 = *(bf16x8*)&u[8];
        }
        __syncthreads();   // tile ready

        bf16x8 fa0 = *(const bf16x8*)af0;
        bf16x8 fa1 = *(const bf16x8*)af1;
        #pragma unroll
        for (int jt = 0; jt < 4; jt++) {
            const int brow = 16 * jt + l15;
            bf16x8 fb0 = *(const bf16x8*)&Bs[brow * 64 + ((q ^ (brow & 7)) * 8)];
            bf16x8 fb1 = *(const bf16x8*)&Bs[brow * 64 + (((q + 4) ^ (brow & 7)) * 8)];
            acc[jt] = __builtin_amdgcn_mfma_f32_16x16x32_bf16(fa0, fb0, acc[jt], 0, 0, 0);
            acc[jt] = __builtin_amdgcn_mfma_f32_16x16x32_bf16(fa1, fb1, acc[jt], 0, 0, 0);
        }
    }
    // epilogue: D layout col=lane&15, row=(lane>>4)*4+reg [m89]
    #pragma unroll
    for (int jt = 0; jt < 4; jt++) {
        const int n = n0 + 16 * jt + l15;
        #pragma unroll
        for (int i = 0; i < 4; i++) {
            const int m = m0 + 16 * wv + q * 4 + i;
            atomicAdd(&C[(size_t)m * N + n], acc[jt][i]);
        }
    }
}

// ---------------- epilogues ----------------
__global__ __launch_bounds__(256) void epi_pos(float* __restrict__ x,
                                               const float* __restrict__ bmap) {
    const int idx = blockIdx.x * 256 + threadIdx.x;
    const int m = idx >> 11, n = idx & 2047;
    float val = x[idx] + bmap[n];
    float jf = (float)n;
    float expo = ((n & 1) ? (jf - 1.0f) : jf) * (1.0f / 2048.0f);
    float ang = (float)m * powf(10000.0f, -expo);
    x[idx] = val + ((n & 1) ? cosf(ang) : sinf(ang));
}

__global__ __launch_bounds__(256) void epi_gelu(float* __restrict__ y,
                                                const float* __restrict__ b1) {
    const int idx = blockIdx.x * 256 + threadIdx.x;
    y[idx] = gelu_f(y[idx] + b1[idx & 8191]);
}

__global__ __launch_bounds__(256) void epi_bias(float* __restrict__ x,
                                                const float* __restrict__ b2) {
    const int idx = blockIdx.x * 256 + threadIdx.x;
    x[idx] += b2[idx & 2047];
}

// =====================================================================
// per-head QKV projection, bf16 MFMA, K=128 (no split, direct store+bias)
// grid: (16 heads, 4 m-tiles, 6 = type*2 + ntile)
// =====================================================================
__global__ __launch_bounds__(256) void qkv_mfma(const float* __restrict__ h,
                                                const float* __restrict__ qw, const float* __restrict__ kw,
                                                const float* __restrict__ vw, const float* __restrict__ qb,
                                                const float* __restrict__ kb, const float* __restrict__ vb,
                                                float* __restrict__ q, float* __restrict__ k,
                                                float* __restrict__ v) {
    __shared__ short As[64 * 64];
    __shared__ short Bs[64 * 64];
    const int head = blockIdx.x, m0 = blockIdx.y * 64;
    const int type = blockIdx.z >> 1, n0 = (blockIdx.z & 1) * 64;
    const float* W; const float* B; float* O;
    if (type == 0)      { W = qw; B = qb; O = q; }
    else if (type == 1) { W = kw; B = kb; O = k; }
    else                { W = vw; B = vb; O = v; }
    W += (size_t)head * DHD * DHD;
    B += head * DHD;
    const int hoff = head * DHD;
    const int tid = threadIdx.x;
    const int wv = tid >> 6, ln = tid & 63;
    const int l15 = ln & 15, qq = ln >> 4;

    f32x4 acc[4];
    #pragma unroll
    for (int j = 0; j < 4; j++) acc[j] = (f32x4){0.f, 0.f, 0.f, 0.f};

    const int am = tid >> 2, akb = (tid & 3) * 16, ac0 = (tid & 3) * 2;
    const int bn = tid & 63, bkb = (tid >> 6) * 16, bc0 = (tid >> 6) * 2;
    short* as0 = &As[am * 64 + ((ac0 ^ (am & 7)) * 8)];
    short* as1 = &As[am * 64 + (((ac0 + 1) ^ (am & 7)) * 8)];
    short* bs0 = &Bs[bn * 64 + ((bc0 ^ (bn & 7)) * 8)];
    short* bs1 = &Bs[bn * 64 + (((bc0 + 1) ^ (bn & 7)) * 8)];
    const int arow = 16 * wv + l15;
    const short* af0 = &As[arow * 64 + ((qq ^ (arow & 7)) * 8)];
    const short* af1 = &As[arow * 64 + (((qq + 4) ^ (arow & 7)) * 8)];

    for (int kc = 0; kc < DHD; kc += 64) {
        const float* ap = h + (size_t)(m0 + am) * DD + hoff + kc + akb;
        float4 a0 = *(const float4*)ap;
        float4 a1 = *(const float4*)(ap + 4);
        float4 a2 = *(const float4*)(ap + 8);
        float4 a3 = *(const float4*)(ap + 12);
        const float* wp = W + (size_t)(kc + bkb) * DHD + n0 + bn;
        float wb[16];
        #pragma unroll
        for (int j = 0; j < 16; j++) wb[j] = wp[j * DHD];

        __syncthreads();
        {
            short t[16] = {f2bf(a0.x), f2bf(a0.y), f2bf(a0.z), f2bf(a0.w),
                           f2bf(a1.x), f2bf(a1.y), f2bf(a1.z), f2bf(a1.w),
                           f2bf(a2.x), f2bf(a2.y), f2bf(a2.z), f2bf(a2.w),
                           f2bf(a3.x), f2bf(a3.y), f2bf(a3.z), f2bf(a3.w)};
            *(bf16x8*)as0 = *(bf16x8*)&t[0];
            *(bf16x8*)as1 = *(bf16x8*)&t[8];
            short u[16];
            #pragma unroll
            for (int j = 0; j < 16; j++) u[j] = f2bf(wb[j]);
            *(bf16x8*)bs0 = *(bf16x8*)&u[0];
            *(bf16x8*)bs1 = *(bf16x8*)&u[8];
        }
        __syncthreads();

        bf16x8 fa0 = *(const bf16x8*)af0;
        bf16x8 fa1 = *(const bf16x8*)af1;
        #pragma unroll
        for (int jt = 0; jt < 4; jt++) {
            const int brow = 16 * jt + l15;
            bf16x8 fb0 = *(const bf16x8*)&Bs[brow * 64 + ((qq ^ (brow & 7)) * 8)];
            bf16x8 fb1 = *(const bf16x8*)&Bs[brow * 64 + (((qq + 4) ^ (brow & 7)) * 8)];
            acc[jt] = __builtin_amdgcn_mfma_f32_16x16x32_bf16(fa0, fb0, acc[jt], 0, 0, 0);
            acc[jt] = __builtin_amdgcn_mfma_f32_16x16x32_bf16(fa1, fb1, acc[jt], 0, 0, 0);
        }
    }
    #pragma unroll
    for (int jt = 0; jt < 4; jt++) {
        const int n = n0 + 16 * jt + l15;
        #pragma unroll
        for (int i = 0; i < 4; i++) {
            const int m = m0 + 16 * wv + qq * 4 + i;
            O[(size_t)m * DD + hoff + n] = acc[jt][i] + B[n];
        }
    }
}

// ---------------- layernorm (one block per row); optionally zero a buffer ----------------
__global__ __launch_bounds__(256) void ln_kernel(const float* __restrict__ xin,
                                                 const float* __restrict__ g,
                                                 const float* __restrict__ b,
                                                 float* __restrict__ out,
                                                 float* __restrict__ zbuf, int zn) {
    __shared__ float red[8];
    const int tid = threadIdx.x;
    for (int i = tid; i < zn; i += 256) zbuf[i] = 0.0f;
    const int row = blockIdx.x;
    const float* xr = xin + row * DD;
    float vals[8];
    float s = 0.0f;
    #pragma unroll
    for (int i = 0; i < 8; i++) { vals[i] = xr[tid + i * 256]; s += vals[i]; }
    #pragma unroll
    for (int o = 32; o > 0; o >>= 1) s += __shfl_down(s, o);
    if ((tid & 63) == 0) red[tid >> 6] = s;
    __syncthreads();
    if (tid == 0) red[4] = (red[0] + red[1] + red[2] + red[3]) * (1.0f / 2048.0f);
    __syncthreads();
    const float mean = red[4];
    float vs = 0.0f;
    #pragma unroll
    for (int i = 0; i < 8; i++) { float d = vals[i] - mean; vs += d * d; }
    #pragma unroll
    for (int o = 32; o > 0; o >>= 1) vs += __shfl_down(vs, o);
    if ((tid & 63) == 0) red[tid >> 6] = vs;
    __syncthreads();
    if (tid == 0) red[5] = rsqrtf((red[0] + red[1] + red[2] + red[3]) * (1.0f / 2048.0f) + 1e-5f);
    __syncthreads();
    const float inv = red[5];
    #pragma unroll
    for (int i = 0; i < 8; i++) {
        int c = tid + i * 256;
        out[row * DD + c] = (vals[i] - mean) * inv * g[c] + b[c];
    }
}

// ---------------- full attention (block 1): x += softmax(qk^T/s) v ----------------
__global__ __launch_bounds__(256) void attn_kernel(const float* __restrict__ q,
                                                   const float* __restrict__ k,
                                                   const float* __restrict__ v,
                                                   float* __restrict__ x) {
    __shared__ float qs[16][129];
    __shared__ float ks[32][129];
    __shared__ float ps[16][257];
    const int head = blockIdx.x, r0 = blockIdx.y * 16;
    const int tid = threadIdx.x, hoff = head * DHD;
    for (int i = tid; i < 16 * 128; i += 256) {
        int r = i >> 7, d = i & 127;
        qs[r][d] = q[(r0 + r) * DD + hoff + d];
    }
    for (int jt = 0; jt < 256; jt += 32) {
        __syncthreads();
        for (int i = tid; i < 32 * 128; i += 256) {
            int r = i >> 7, d = i & 127;
            ks[r][d] = k[(jt + r) * DD + hoff + d];
        }
        __syncthreads();
        #pragma unroll
        for (int idx = tid; idx < 16 * 32; idx += 256) {
            int i = idx >> 5, j = idx & 31;
            float s = 0.0f;
            #pragma unroll
            for (int d = 0; d < 128; d++) s += qs[i][d] * ks[j][d];
            ps[i][jt + j] = s * INV_SQRT_DH;
        }
    }
    __syncthreads();
    if (tid < 16) {
        float mx = -1e30f;
        for (int j = 0; j < 256; j++) mx = fmaxf(mx, ps[tid][j]);
        float sm = 0.0f;
        for (int j = 0; j < 256; j++) { float e = __expf(ps[tid][j] - mx); ps[tid][j] = e; sm += e; }
        float inv = 1.0f / sm;
        for (int j = 0; j < 256; j++) ps[tid][j] *= inv;
    }
    __syncthreads();
    for (int idx = tid; idx < 16 * 128; idx += 256) {
        int i = idx >> 7, e = idx & 127;
        float acc = 0.0f;
        #pragma unroll 8
        for (int j = 0; j < 256; j++) acc += ps[i][j] * v[j * DD + hoff + e];
        x[(r0 + i) * DD + hoff + e] += acc;
    }
}

// ---------------- block-2 attention, query row 0 only ----------------
__global__ __launch_bounds__(256) void attn0_kernel(const float* __restrict__ q,
                                                    const float* __restrict__ k,
                                                    const float* __restrict__ v,
                                                    float* __restrict__ x) {
    __shared__ float q0[128];
    __shared__ float p[256];
    __shared__ float red[8];
    const int h = blockIdx.x, tid = threadIdx.x, hoff = h * DHD;
    if (tid < 128) q0[tid] = q[hoff + tid];
    __syncthreads();
    const float* kr = k + tid * DD + hoff;
    float s = 0.0f;
    #pragma unroll 8
    for (int d = 0; d < 128; d++) s += q0[d] * kr[d];
    s *= INV_SQRT_DH;
    float m = s;
    #pragma unroll
    for (int o = 32; o > 0; o >>= 1) m = fmaxf(m, __shfl_down(m, o));
    if ((tid & 63) == 0) red[tid >> 6] = m;
    __syncthreads();
    if (tid == 0) red[4] = fmaxf(fmaxf(red[0], red[1]), fmaxf(red[2], red[3]));
    __syncthreads();
    const float mx = red[4];
    float e = __expf(s - mx);
    p[tid] = e;
    float t = e;
    #pragma unroll
    for (int o = 32; o > 0; o >>= 1) t += __shfl_down(t, o);
    if ((tid & 63) == 0) red[tid >> 6] = t;
    __syncthreads();
    if (tid == 0) red[5] = red[0] + red[1] + red[2] + red[3];
    __syncthreads();
    const float inv = 1.0f / red[5];
    if (tid < 128) {
        float acc = 0.0f;
        #pragma unroll 8
        for (int j = 0; j < 256; j++) acc += p[j] * v[j * DD + hoff + tid];
        x[hoff + tid] += acc * inv;
    }
}

// ---------------- block-2 MLP GEMVs (token 0 only) ----------------
__global__ __launch_bounds__(256) void gemv1_kernel(const float* __restrict__ h2,
                                                    const float* __restrict__ w1,
                                                    float* __restrict__ y) {
    const int n = blockIdx.x * 256 + threadIdx.x;
    const int k0 = blockIdx.y * 256;
    float s = 0.0f;
    #pragma unroll 8
    for (int k = 0; k < 256; k++) s += h2[k0 + k] * w1[(size_t)(k0 + k) * MLPD + n];
    atomicAdd(&y[n], s);
}

__global__ __launch_bounds__(256) void gelu_bias_kernel(float* __restrict__ y,
                                                        const float* __restrict__ b1) {
    const int n = blockIdx.x * 256 + threadIdx.x;
    y[n] = gelu_f(y[n] + b1[n]);
}

__global__ __launch_bounds__(256) void gemv2_kernel(const float* __restrict__ y1,
                                                    const float* __restrict__ w2,
                                                    float* __restrict__ x) {
    const int m = blockIdx.x * 256 + threadIdx.x;
    const int k0 = blockIdx.y * 512;
    float s = 0.0f;
    #pragma unroll 8
    for (int k = 0; k < 512; k++) s += y1[k0 + k] * w2[(size_t)(k0 + k) * DD + m];
    atomicAdd(&x[m], s);
}

// ---------------- head: sigmoid(cls . head_w + head_b), copy memory ----------------
__global__ __launch_bounds__(256) void head_kernel(const float* __restrict__ x,
                                                   const float* __restrict__ b2l,
                                                   const float* __restrict__ hw,
                                                   const float* __restrict__ hb,
                                                   const float* __restrict__ mem,
                                                   float* __restrict__ out) {
    __shared__ float red[8];
    const int tid = threadIdx.x;
    float s = 0.0f;
    for (int m = tid; m < 2048; m += 256) s += (x[m] + b2l[m]) * hw[m];
    #pragma unroll
    for (int o = 32; o > 0; o >>= 1) s += __shfl_down(s, o);
    if ((tid & 63) == 0) red[tid >> 6] = s;
    __syncthreads();
    if (tid == 0) {
        float t = red[0] + red[1] + red[2] + red[3];
        out[0] = 1.0f / (1.0f + __expf(-(t + hb[0])));
    }
    if (tid < 8) out[1 + tid] = mem[tid];
}

extern "C" void kernel_launch(void* const* d_in, const int* in_sizes, int n_in,
                              void* d_out, int out_size, void* d_ws, size_t ws_size,
                              hipStream_t stream) {
    const float* images = (const float*)d_in[0];
    const float* memory = (const float*)d_in[1];
    const float* wmap   = (const float*)d_in[2];
    const float* bmap   = (const float*)d_in[3];
    const float* ln1_g  = (const float*)d_in[4];
    const float* ln1_b  = (const float*)d_in[5];
    const float* qw     = (const float*)d_in[6];
    const float* qb     = (const float*)d_in[7];
    const float* kw     = (const float*)d_in[8];
    const float* kb     = (const float*)d_in[9];
    const float* vw     = (const float*)d_in[10];
    const float* vb     = (const float*)d_in[11];
    const float* ln2_g  = (const float*)d_in[12];
    const float* ln2_b  = (const float*)d_in[13];
    const float* w1     = (const float*)d_in[14];
    const float* b1     = (const float*)d_in[15];
    const float* w2     = (const float*)d_in[16];
    const float* b2     = (const float*)d_in[17];
    const float* head_w = (const float*)d_in[18];
    const float* head_b = (const float*)d_in[19];
    float* out = (float*)d_out;

    float* ws = (float*)d_ws;
    float* x     = ws;                    // 256*2048
    float* h     = x + SQ * DD;           // 256*2048
    float* q     = h + SQ * DD;           // 256*2048
    float* k     = q + SQ * DD;
    float* v     = k + SQ * DD;
    float* y1    = v + SQ * DD;           // 256*8192
    float* y1row = y1 + SQ * MLPD;        // 8192
    float* h2row = y1row + MLPD;          // 2048

    // ---- patch embed: x = images @ wmap (split-K atomic) + bias + posemb ----
    hipMemsetAsync(x, 0, (size_t)SQ * DD * sizeof(float), stream);
    gemm_splitk<<<dim3(DD / 64, SQ / 64, 8), 256, 0, stream>>>(images, wmap, x, DD, KIN, 512);
    epi_pos<<<SQ * DD / 256, 256, 0, stream>>>(x, bmap);

    for (int l = 0; l < 2; l++) {
        const size_t wofs = (size_t)l * NHD * DHD * DHD;
        const size_t bofs = (size_t)l * NHD * DHD;
        ln_kernel<<<SQ, 256, 0, stream>>>(x, ln1_g + l * DD, ln1_b + l * DD, h, nullptr, 0);
        qkv_mfma<<<dim3(NHD, SQ / 64, 6), 256, 0, stream>>>(h, qw + wofs, kw + wofs, vw + wofs,
                                                            qb + bofs, kb + bofs, vb + bofs,
                                                            q, k, v);
        if (l == 0) {
            attn_kernel<<<dim3(NHD, SQ / 16), 256, 0, stream>>>(q, k, v, x);
            ln_kernel<<<SQ, 256, 0, stream>>>(x, ln2_g, ln2_b, h, nullptr, 0);
            // MLP1: y1 = gelu(h @ w1 + b1)
            hipMemsetAsync(y1, 0, (size_t)SQ * MLPD * sizeof(float), stream);
            gemm_splitk<<<dim3(MLPD / 64, SQ / 64, 2), 256, 0, stream>>>(h, w1, y1, MLPD, DD, 1024);
            epi_gelu<<<SQ * MLPD / 256, 256, 0, stream>>>(y1, b1);
            // MLP2: x += y1 @ w2 + b2
            gemm_splitk<<<dim3(DD / 64, SQ / 64, 8), 256, 0, stream>>>(y1, w2, x, DD, MLPD, 1024);
            epi_bias<<<SQ * DD / 256, 256, 0, stream>>>(x, b2);
        } else {
            attn0_kernel<<<NHD, 256, 0, stream>>>(q, k, v, x);
            // LN2 of row 0 only; also zero y1row for gemv accumulation
            ln_kernel<<<1, 256, 0, stream>>>(x, ln2_g + DD, ln2_b + DD, h2row, y1row, MLPD);
            gemv1_kernel<<<dim3(MLPD / 256, 8), 256, 0, stream>>>(h2row, w1 + (size_t)DD * MLPD, y1row);
            gelu_bias_kernel<<<MLPD / 256, 256, 0, stream>>>(y1row, b1 + MLPD);
            gemv2_kernel<<<dim3(DD / 256, 16), 256, 0, stream>>>(y1row, w2 + (size_t)DD * MLPD, x);
            head_kernel<<<1, 256, 0, stream>>>(x, b2 + DD, head_w, head_b, memory, out);
        }
    }
}

// Round 4
// 507.641 us; speedup vs baseline: 4.7684x; 1.2137x over previous
//
#include <hip/hip_runtime.h>
#include <math.h>

// ---------------- constants ----------------
#define SQ   256          // tokens
#define DD   2048         // model dim
#define NHD  16           // heads
#define DHD  128          // head dim
#define MLPD 8192
#define KIN  4096         // INPUT_D
#define INV_SQRT_DH 0.08838834764831845f

typedef __attribute__((ext_vector_type(8))) short bf16x8;
typedef __attribute__((ext_vector_type(4))) float f32x4;

__device__ __forceinline__ float gelu_f(float x) {
    return 0.5f * x * (1.0f + erff(x * 0.70710678118654752f));
}

// float -> bf16 round-to-nearest-even
__device__ __forceinline__ short f2bf(float f) {
    unsigned u = __float_as_uint(f);
    unsigned r = (u + 0x7fffu + ((u >> 16) & 1u)) >> 16;
    return (short)r;
}

// =====================================================================
// Split-K bf16 MFMA GEMM partial: atomicAdd(C, A[64m x KC] @ W[KC x 64n])
// =====================================================================
__global__ __launch_bounds__(256) void gemm_splitk(const float* __restrict__ A,
                                                   const float* __restrict__ W,
                                                   float* __restrict__ C,
                                                   int N, int K, int KC) {
    __shared__ short As[64 * 64];
    __shared__ short Bs[64 * 64];
    const int tid = threadIdx.x;
    const int n0 = blockIdx.x * 64, m0 = blockIdx.y * 64;
    const int kstart = blockIdx.z * KC;
    const int wv = tid >> 6, ln = tid & 63;
    const int l15 = ln & 15, q = ln >> 4;

    f32x4 acc[4];
    #pragma unroll
    for (int j = 0; j < 4; j++) acc[j] = (f32x4){0.f, 0.f, 0.f, 0.f};

    const int am = tid >> 2, akb = (tid & 3) * 16, ac0 = (tid & 3) * 2;
    const int bn = tid & 63, bkb = (tid >> 6) * 16, bc0 = (tid >> 6) * 2;
    short* as0 = &As[am * 64 + ((ac0 ^ (am & 7)) * 8)];
    short* as1 = &As[am * 64 + (((ac0 + 1) ^ (am & 7)) * 8)];
    short* bs0 = &Bs[bn * 64 + ((bc0 ^ (bn & 7)) * 8)];
    short* bs1 = &Bs[bn * 64 + (((bc0 + 1) ^ (bn & 7)) * 8)];
    const int arow = 16 * wv + l15;
    const short* af0 = &As[arow * 64 + ((q ^ (arow & 7)) * 8)];
    const short* af1 = &As[arow * 64 + (((q + 4) ^ (arow & 7)) * 8)];

    for (int kc = kstart; kc < kstart + KC; kc += 64) {
        const float* ap = A + (size_t)(m0 + am) * K + kc + akb;
        float4 a0 = *(const float4*)ap;
        float4 a1 = *(const float4*)(ap + 4);
        float4 a2 = *(const float4*)(ap + 8);
        float4 a3 = *(const float4*)(ap + 12);
        const float* wp = W + (size_t)(kc + bkb) * N + n0 + bn;
        float wb[16];
        #pragma unroll
        for (int j = 0; j < 16; j++) wb[j] = wp[(size_t)j * N];

        __syncthreads();
        {
            short t[16] = {f2bf(a0.x), f2bf(a0.y), f2bf(a0.z), f2bf(a0.w),
                           f2bf(a1.x), f2bf(a1.y), f2bf(a1.z), f2bf(a1.w),
                           f2bf(a2.x), f2bf(a2.y), f2bf(a2.z), f2bf(a2.w),
                           f2bf(a3.x), f2bf(a3.y), f2bf(a3.z), f2bf(a3.w)};
            *(bf16x8*)as0 = *(bf16x8*)&t[0];
            *(bf16x8*)as1 = *(bf16x8*)&t[8];
            short u[16];
            #pragma unroll
            for (int j = 0; j < 16; j++) u[j] = f2bf(wb[j]);
            *(bf16x8*)bs0 = *(bf16x8*)&u[0];
            *(bf16x8*)bs1 = *(bf16x8*)&u[8];
        }
        __syncthreads();

        bf16x8 fa0 = *(const bf16x8*)af0;
        bf16x8 fa1 = *(const bf16x8*)af1;
        #pragma unroll
        for (int jt = 0; jt < 4; jt++) {
            const int brow = 16 * jt + l15;
            bf16x8 fb0 = *(const bf16x8*)&Bs[brow * 64 + ((q ^ (brow & 7)) * 8)];
            bf16x8 fb1 = *(const bf16x8*)&Bs[brow * 64 + (((q + 4) ^ (brow & 7)) * 8)];
            acc[jt] = __builtin_amdgcn_mfma_f32_16x16x32_bf16(fa0, fb0, acc[jt], 0, 0, 0);
            acc[jt] = __builtin_amdgcn_mfma_f32_16x16x32_bf16(fa1, fb1, acc[jt], 0, 0, 0);
        }
    }
    #pragma unroll
    for (int jt = 0; jt < 4; jt++) {
        const int n = n0 + 16 * jt + l15;
        #pragma unroll
        for (int i = 0; i < 4; i++) {
            const int m = m0 + 16 * wv + q * 4 + i;
            atomicAdd(&C[(size_t)m * N + n], acc[jt][i]);
        }
    }
}

// ---------------- epilogues ----------------
__global__ __launch_bounds__(256) void epi_pos(float* __restrict__ x,
                                               const float* __restrict__ bmap) {
    const int idx = blockIdx.x * 256 + threadIdx.x;
    const int m = idx >> 11, n = idx & 2047;
    float val = x[idx] + bmap[n];
    float jf = (float)n;
    float expo = ((n & 1) ? (jf - 1.0f) : jf) * (1.0f / 2048.0f);
    float ang = (float)m * powf(10000.0f, -expo);
    x[idx] = val + ((n & 1) ? cosf(ang) : sinf(ang));
}

__global__ __launch_bounds__(256) void epi_gelu(float* __restrict__ y,
                                                const float* __restrict__ b1) {
    const int idx = blockIdx.x * 256 + threadIdx.x;
    y[idx] = gelu_f(y[idx] + b1[idx & 8191]);
}

__global__ __launch_bounds__(256) void epi_bias(float* __restrict__ x,
                                                const float* __restrict__ b2) {
    const int idx = blockIdx.x * 256 + threadIdx.x;
    x[idx] += b2[idx & 2047];
}

// =====================================================================
// per-head QKV projection, bf16 MFMA, K=128
// =====================================================================
__global__ __launch_bounds__(256) void qkv_mfma(const float* __restrict__ h,
                                                const float* __restrict__ qw, const float* __restrict__ kw,
                                                const float* __restrict__ vw, const float* __restrict__ qb,
                                                const float* __restrict__ kb, const float* __restrict__ vb,
                                                float* __restrict__ q, float* __restrict__ k,
                                                float* __restrict__ v) {
    __shared__ short As[64 * 64];
    __shared__ short Bs[64 * 64];
    const int head = blockIdx.x, m0 = blockIdx.y * 64;
    const int type = blockIdx.z >> 1, n0 = (blockIdx.z & 1) * 64;
    const float* W; const float* B; float* O;
    if (type == 0)      { W = qw; B = qb; O = q; }
    else if (type == 1) { W = kw; B = kb; O = k; }
    else                { W = vw; B = vb; O = v; }
    W += (size_t)head * DHD * DHD;
    B += head * DHD;
    const int hoff = head * DHD;
    const int tid = threadIdx.x;
    const int wv = tid >> 6, ln = tid & 63;
    const int l15 = ln & 15, qq = ln >> 4;

    f32x4 acc[4];
    #pragma unroll
    for (int j = 0; j < 4; j++) acc[j] = (f32x4){0.f, 0.f, 0.f, 0.f};

    const int am = tid >> 2, akb = (tid & 3) * 16, ac0 = (tid & 3) * 2;
    const int bn = tid & 63, bkb = (tid >> 6) * 16, bc0 = (tid >> 6) * 2;
    short* as0 = &As[am * 64 + ((ac0 ^ (am & 7)) * 8)];
    short* as1 = &As[am * 64 + (((ac0 + 1) ^ (am & 7)) * 8)];
    short* bs0 = &Bs[bn * 64 + ((bc0 ^ (bn & 7)) * 8)];
    short* bs1 = &Bs[bn * 64 + (((bc0 + 1) ^ (bn & 7)) * 8)];
    const int arow = 16 * wv + l15;
    const short* af0 = &As[arow * 64 + ((qq ^ (arow & 7)) * 8)];
    const short* af1 = &As[arow * 64 + (((qq + 4) ^ (arow & 7)) * 8)];

    for (int kc = 0; kc < DHD; kc += 64) {
        const float* ap = h + (size_t)(m0 + am) * DD + hoff + kc + akb;
        float4 a0 = *(const float4*)ap;
        float4 a1 = *(const float4*)(ap + 4);
        float4 a2 = *(const float4*)(ap + 8);
        float4 a3 = *(const float4*)(ap + 12);
        const float* wp = W + (size_t)(kc + bkb) * DHD + n0 + bn;
        float wb[16];
        #pragma unroll
        for (int j = 0; j < 16; j++) wb[j] = wp[j * DHD];

        __syncthreads();
        {
            short t[16] = {f2bf(a0.x), f2bf(a0.y), f2bf(a0.z), f2bf(a0.w),
                           f2bf(a1.x), f2bf(a1.y), f2bf(a1.z), f2bf(a1.w),
                           f2bf(a2.x), f2bf(a2.y), f2bf(a2.z), f2bf(a2.w),
                           f2bf(a3.x), f2bf(a3.y), f2bf(a3.z), f2bf(a3.w)};
            *(bf16x8*)as0 = *(bf16x8*)&t[0];
            *(bf16x8*)as1 = *(bf16x8*)&t[8];
            short u[16];
            #pragma unroll
            for (int j = 0; j < 16; j++) u[j] = f2bf(wb[j]);
            *(bf16x8*)bs0 = *(bf16x8*)&u[0];
            *(bf16x8*)bs1 = *(bf16x8*)&u[8];
        }
        __syncthreads();

        bf16x8 fa0 = *(const bf16x8*)af0;
        bf16x8 fa1 = *(const bf16x8*)af1;
        #pragma unroll
        for (int jt = 0; jt < 4; jt++) {
            const int brow = 16 * jt + l15;
            bf16x8 fb0 = *(const bf16x8*)&Bs[brow * 64 + ((qq ^ (brow & 7)) * 8)];
            bf16x8 fb1 = *(const bf16x8*)&Bs[brow * 64 + (((qq + 4) ^ (brow & 7)) * 8)];
            acc[jt] = __builtin_amdgcn_mfma_f32_16x16x32_bf16(fa0, fb0, acc[jt], 0, 0, 0);
            acc[jt] = __builtin_amdgcn_mfma_f32_16x16x32_bf16(fa1, fb1, acc[jt], 0, 0, 0);
        }
    }
    #pragma unroll
    for (int jt = 0; jt < 4; jt++) {
        const int n = n0 + 16 * jt + l15;
        #pragma unroll
        for (int i = 0; i < 4; i++) {
            const int m = m0 + 16 * wv + qq * 4 + i;
            O[(size_t)m * DD + hoff + n] = acc[jt][i] + B[n];
        }
    }
}

// =====================================================================
// block-1 attention via MFMA: x += softmax(QK^T * scale) V
// grid: (4 q-tiles of 64 rows, 16 heads), 256 threads = 4 waves.
// Per wave: 16 q-rows. QK^T: Q-frags from global, K staged per 64-key
// quarter (LDS [64][136], uniform bank groups). Softmax in registers
// (shfl_xor over 16-lane groups). P -> LDS bf16 (chunk-XOR swizzle).
// PV: V^T staged per quarter (LDS [128][72]), MFMA.
// =====================================================================
__global__ __launch_bounds__(256) void attn_mfma(const float* __restrict__ q,
                                                 const float* __restrict__ k,
                                                 const float* __restrict__ v,
                                                 float* __restrict__ x) {
    __shared__ short P[64 * 272];   // [row][col chunks xor row&7], 34.8 KB
    __shared__ short ST[9216];      // K quarter [64][136] / Vt quarter [128][72]
    const int head = blockIdx.y, r0 = blockIdx.x * 64;
    const int hoff = head * DHD;
    const int tid = threadIdx.x;
    const int wv = tid >> 6, ln = tid & 63;
    const int l15 = ln & 15, qd = ln >> 4;

    // Q A-fragments direct from global: af[s] covers k = s*32 + qd*8 + j
    bf16x8 af[4];
    {
        const float* qp = q + (size_t)(r0 + 16 * wv + l15) * DD + hoff + qd * 8;
        #pragma unroll
        for (int s = 0; s < 4; s++) {
            float4 f0 = *(const float4*)(qp + s * 32);
            float4 f1 = *(const float4*)(qp + s * 32 + 4);
            short t[8] = {f2bf(f0.x), f2bf(f0.y), f2bf(f0.z), f2bf(f0.w),
                          f2bf(f1.x), f2bf(f1.y), f2bf(f1.z), f2bf(f1.w)};
            af[s] = *(bf16x8*)t;
        }
    }

    f32x4 sacc[16];
    #pragma unroll
    for (int i = 0; i < 16; i++) sacc[i] = (f32x4){0.f, 0.f, 0.f, 0.f};

    // ---- QK^T over 4 key-quarters ----
    const int skey = tid >> 2, scol = (tid & 3) * 32;
    for (int kq = 0; kq < 4; kq++) {
        const float* kp = k + (size_t)(kq * 64 + skey) * DD + hoff + scol;
        float4 f[8];
        #pragma unroll
        for (int a = 0; a < 8; a++) f[a] = *(const float4*)(kp + a * 4);
        if (kq) __syncthreads();         // previous quarter fully consumed
        #pragma unroll
        for (int a = 0; a < 4; a++) {
            short t[8] = {f2bf(f[2*a].x), f2bf(f[2*a].y), f2bf(f[2*a].z), f2bf(f[2*a].w),
                          f2bf(f[2*a+1].x), f2bf(f[2*a+1].y), f2bf(f[2*a+1].z), f2bf(f[2*a+1].w)};
            *(bf16x8*)&ST[skey * 136 + scol + a * 8] = *(bf16x8*)t;
        }
        __syncthreads();
        #pragma unroll
        for (int nl = 0; nl < 4; nl++) {
            #pragma unroll
            for (int s = 0; s < 4; s++) {
                bf16x8 bfr = *(const bf16x8*)&ST[(nl * 16 + l15) * 136 + s * 32 + qd * 8];
                sacc[kq * 4 + nl] = __builtin_amdgcn_mfma_f32_16x16x32_bf16(af[s], bfr, sacc[kq * 4 + nl], 0, 0, 0);
            }
        }
    }

    // ---- softmax in registers: row r = 16wv + 4qd + i, cols nt*16 + l15 ----
    float inv_s[4];
    #pragma unroll
    for (int i = 0; i < 4; i++) {
        float m = -1e30f;
        #pragma unroll
        for (int nt = 0; nt < 16; nt++) m = fmaxf(m, sacc[nt][i]);
        m = fmaxf(m, __shfl_xor(m, 1));
        m = fmaxf(m, __shfl_xor(m, 2));
        m = fmaxf(m, __shfl_xor(m, 4));
        m = fmaxf(m, __shfl_xor(m, 8));
        float sum = 0.f;
        #pragma unroll
        for (int nt = 0; nt < 16; nt++) {
            float e = __expf((sacc[nt][i] - m) * INV_SQRT_DH);
            sacc[nt][i] = e;
            sum += e;
        }
        sum += __shfl_xor(sum, 1);
        sum += __shfl_xor(sum, 2);
        sum += __shfl_xor(sum, 4);
        sum += __shfl_xor(sum, 8);
        inv_s[i] = 1.0f / sum;
    }
    // write P (bf16) with chunk-XOR layout
    #pragma unroll
    for (int nt = 0; nt < 16; nt++) {
        const int col = nt * 16 + l15;
        const int chunk = col >> 3, c7 = col & 7;
        #pragma unroll
        for (int i = 0; i < 4; i++) {
            const int row = 16 * wv + 4 * qd + i;
            P[row * 272 + ((chunk ^ (row & 7)) * 8) + c7] = f2bf(sacc[nt][i] * inv_s[i]);
        }
    }
    __syncthreads();   // P visible; last QK reads of ST done

    // ---- PV over 4 key-quarters ----
    f32x4 oacc[8];
    #pragma unroll
    for (int e = 0; e < 8; e++) oacc[e] = (f32x4){0.f, 0.f, 0.f, 0.f};

    const int ve = tid & 127, vks = (tid >> 7) * 32;
    for (int kq = 0; kq < 4; kq++) {
        float vv[32];
        #pragma unroll
        for (int j = 0; j < 32; j++)
            vv[j] = v[(size_t)(kq * 64 + vks + j) * DD + hoff + ve];
        if (kq) __syncthreads();
        #pragma unroll
        for (int c = 0; c < 4; c++) {
            short t[8];
            #pragma unroll
            for (int b = 0; b < 8; b++) t[b] = f2bf(vv[c * 8 + b]);
            const int ch = (vks >> 3) + c;       // key chunk 0..7 in quarter
            *(bf16x8*)&ST[ve * 72 + ((ch ^ (ve & 7)) * 8)] = *(bf16x8*)t;
        }
        __syncthreads();
        #pragma unroll
        for (int s = 0; s < 2; s++) {
            const int row = 16 * wv + l15;
            const int pc = kq * 8 + s * 4 + qd;          // P col chunk
            bf16x8 pa = *(const bf16x8*)&P[row * 272 + ((pc ^ (row & 7)) * 8)];
            #pragma unroll
            for (int et = 0; et < 8; et++) {
                const int er = et * 16 + l15;
                const int vc = s * 4 + qd;               // Vt key chunk
                bf16x8 vb = *(const bf16x8*)&ST[er * 72 + ((vc ^ (er & 7)) * 8)];
                oacc[et] = __builtin_amdgcn_mfma_f32_16x16x32_bf16(pa, vb, oacc[et], 0, 0, 0);
            }
        }
    }
    // epilogue: x += O (C layout: row = qd*4+i, col = l15)
    #pragma unroll
    for (int et = 0; et < 8; et++) {
        const int e = et * 16 + l15;
        #pragma unroll
        for (int i = 0; i < 4; i++) {
            const int row = r0 + 16 * wv + 4 * qd + i;
            x[(size_t)row * DD + hoff + e] += oacc[et][i];
        }
    }
}

// ---------------- layernorm (one block per row); optionally zero a buffer ----------------
__global__ __launch_bounds__(256) void ln_kernel(const float* __restrict__ xin,
                                                 const float* __restrict__ g,
                                                 const float* __restrict__ b,
                                                 float* __restrict__ out,
                                                 float* __restrict__ zbuf, int zn) {
    __shared__ float red[8];
    const int tid = threadIdx.x;
    for (int i = tid; i < zn; i += 256) zbuf[i] = 0.0f;
    const int row = blockIdx.x;
    const float* xr = xin + row * DD;
    float vals[8];
    float s = 0.0f;
    #pragma unroll
    for (int i = 0; i < 8; i++) { vals[i] = xr[tid + i * 256]; s += vals[i]; }
    #pragma unroll
    for (int o = 32; o > 0; o >>= 1) s += __shfl_down(s, o);
    if ((tid & 63) == 0) red[tid >> 6] = s;
    __syncthreads();
    if (tid == 0) red[4] = (red[0] + red[1] + red[2] + red[3]) * (1.0f / 2048.0f);
    __syncthreads();
    const float mean = red[4];
    float vs = 0.0f;
    #pragma unroll
    for (int i = 0; i < 8; i++) { float d = vals[i] - mean; vs += d * d; }
    #pragma unroll
    for (int o = 32; o > 0; o >>= 1) vs += __shfl_down(vs, o);
    if ((tid & 63) == 0) red[tid >> 6] = vs;
    __syncthreads();
    if (tid == 0) red[5] = rsqrtf((red[0] + red[1] + red[2] + red[3]) * (1.0f / 2048.0f) + 1e-5f);
    __syncthreads();
    const float inv = red[5];
    #pragma unroll
    for (int i = 0; i < 8; i++) {
        int c = tid + i * 256;
        out[row * DD + c] = (vals[i] - mean) * inv * g[c] + b[c];
    }
}

// ---------------- block-2 attention, query row 0 only ----------------
__global__ __launch_bounds__(256) void attn0_kernel(const float* __restrict__ q,
                                                    const float* __restrict__ k,
                                                    const float* __restrict__ v,
                                                    float* __restrict__ x) {
    __shared__ float q0[128];
    __shared__ float p[256];
    __shared__ float red[8];
    const int h = blockIdx.x, tid = threadIdx.x, hoff = h * DHD;
    if (tid < 128) q0[tid] = q[hoff + tid];
    __syncthreads();
    const float* kr = k + tid * DD + hoff;
    float s = 0.0f;
    #pragma unroll 8
    for (int d = 0; d < 128; d++) s += q0[d] * kr[d];
    s *= INV_SQRT_DH;
    float m = s;
    #pragma unroll
    for (int o = 32; o > 0; o >>= 1) m = fmaxf(m, __shfl_down(m, o));
    if ((tid & 63) == 0) red[tid >> 6] = m;
    __syncthreads();
    if (tid == 0) red[4] = fmaxf(fmaxf(red[0], red[1]), fmaxf(red[2], red[3]));
    __syncthreads();
    const float mx = red[4];
    float e = __expf(s - mx);
    p[tid] = e;
    float t = e;
    #pragma unroll
    for (int o = 32; o > 0; o >>= 1) t += __shfl_down(t, o);
    if ((tid & 63) == 0) red[tid >> 6] = t;
    __syncthreads();
    if (tid == 0) red[5] = red[0] + red[1] + red[2] + red[3];
    __syncthreads();
    const float inv = 1.0f / red[5];
    if (tid < 128) {
        float acc = 0.0f;
        #pragma unroll 8
        for (int j = 0; j < 256; j++) acc += p[j] * v[j * DD + hoff + tid];
        x[hoff + tid] += acc * inv;
    }
}

// ---------------- block-2 MLP GEMVs (token 0 only) ----------------
__global__ __launch_bounds__(256) void gemv1_kernel(const float* __restrict__ h2,
                                                    const float* __restrict__ w1,
                                                    float* __restrict__ y) {
    const int n = blockIdx.x * 256 + threadIdx.x;
    const int k0 = blockIdx.y * 64;
    float s = 0.0f;
    #pragma unroll 8
    for (int k = 0; k < 64; k++) s += h2[k0 + k] * w1[(size_t)(k0 + k) * MLPD + n];
    atomicAdd(&y[n], s);
}

__global__ __launch_bounds__(256) void gelu_bias_kernel(float* __restrict__ y,
                                                        const float* __restrict__ b1) {
    const int n = blockIdx.x * 256 + threadIdx.x;
    y[n] = gelu_f(y[n] + b1[n]);
}

__global__ __launch_bounds__(256) void gemv2_kernel(const float* __restrict__ y1,
                                                    const float* __restrict__ w2,
                                                    float* __restrict__ x) {
    const int m = blockIdx.x * 256 + threadIdx.x;
    const int k0 = blockIdx.y * 256;
    float s = 0.0f;
    #pragma unroll 8
    for (int k = 0; k < 256; k++) s += y1[k0 + k] * w2[(size_t)(k0 + k) * DD + m];
    atomicAdd(&x[m], s);
}

// ---------------- head: sigmoid(cls . head_w + head_b), copy memory ----------------
__global__ __launch_bounds__(256) void head_kernel(const float* __restrict__ x,
                                                   const float* __restrict__ b2l,
                                                   const float* __restrict__ hw,
                                                   const float* __restrict__ hb,
                                                   const float* __restrict__ mem,
                                                   float* __restrict__ out) {
    __shared__ float red[8];
    const int tid = threadIdx.x;
    float s = 0.0f;
    for (int m = tid; m < 2048; m += 256) s += (x[m] + b2l[m]) * hw[m];
    #pragma unroll
    for (int o = 32; o > 0; o >>= 1) s += __shfl_down(s, o);
    if ((tid & 63) == 0) red[tid >> 6] = s;
    __syncthreads();
    if (tid == 0) {
        float t = red[0] + red[1] + red[2] + red[3];
        out[0] = 1.0f / (1.0f + __expf(-(t + hb[0])));
    }
    if (tid < 8) out[1 + tid] = mem[tid];
}

extern "C" void kernel_launch(void* const* d_in, const int* in_sizes, int n_in,
                              void* d_out, int out_size, void* d_ws, size_t ws_size,
                              hipStream_t stream) {
    const float* images = (const float*)d_in[0];
    const float* memory = (const float*)d_in[1];
    const float* wmap   = (const float*)d_in[2];
    const float* bmap   = (const float*)d_in[3];
    const float* ln1_g  = (const float*)d_in[4];
    const float* ln1_b  = (const float*)d_in[5];
    const float* qw     = (const float*)d_in[6];
    const float* qb     = (const float*)d_in[7];
    const float* kw     = (const float*)d_in[8];
    const float* kb     = (const float*)d_in[9];
    const float* vw     = (const float*)d_in[10];
    const float* vb     = (const float*)d_in[11];
    const float* ln2_g  = (const float*)d_in[12];
    const float* ln2_b  = (const float*)d_in[13];
    const float* w1     = (const float*)d_in[14];
    const float* b1     = (const float*)d_in[15];
    const float* w2     = (const float*)d_in[16];
    const float* b2     = (const float*)d_in[17];
    const float* head_w = (const float*)d_in[18];
    const float* head_b = (const float*)d_in[19];
    float* out = (float*)d_out;

    float* ws = (float*)d_ws;
    float* x     = ws;                    // 256*2048
    float* h     = x + SQ * DD;           // 256*2048
    float* q     = h + SQ * DD;           // 256*2048
    float* k     = q + SQ * DD;
    float* v     = k + SQ * DD;
    float* y1    = v + SQ * DD;           // 256*8192
    float* y1row = y1 + SQ * MLPD;        // 8192
    float* h2row = y1row + MLPD;          // 2048

    // ---- patch embed: x = images @ wmap (split-K atomic) + bias + posemb ----
    hipMemsetAsync(x, 0, (size_t)SQ * DD * sizeof(float), stream);
    gemm_splitk<<<dim3(DD / 64, SQ / 64, 8), 256, 0, stream>>>(images, wmap, x, DD, KIN, 512);
    epi_pos<<<SQ * DD / 256, 256, 0, stream>>>(x, bmap);

    for (int l = 0; l < 2; l++) {
        const size_t wofs = (size_t)l * NHD * DHD * DHD;
        const size_t bofs = (size_t)l * NHD * DHD;
        ln_kernel<<<SQ, 256, 0, stream>>>(x, ln1_g + l * DD, ln1_b + l * DD, h, nullptr, 0);
        qkv_mfma<<<dim3(NHD, SQ / 64, 6), 256, 0, stream>>>(h, qw + wofs, kw + wofs, vw + wofs,
                                                            qb + bofs, kb + bofs, vb + bofs,
                                                            q, k, v);
        if (l == 0) {
            attn_mfma<<<dim3(SQ / 64, NHD), 256, 0, stream>>>(q, k, v, x);
            ln_kernel<<<SQ, 256, 0, stream>>>(x, ln2_g, ln2_b, h, nullptr, 0);
            // MLP1: y1 = gelu(h @ w1 + b1)
            hipMemsetAsync(y1, 0, (size_t)SQ * MLPD * sizeof(float), stream);
            gemm_splitk<<<dim3(MLPD / 64, SQ / 64, 2), 256, 0, stream>>>(h, w1, y1, MLPD, DD, 1024);
            epi_gelu<<<SQ * MLPD / 256, 256, 0, stream>>>(y1, b1);
            // MLP2: x += y1 @ w2 + b2
            gemm_splitk<<<dim3(DD / 64, SQ / 64, 8), 256, 0, stream>>>(y1, w2, x, DD, MLPD, 1024);
            epi_bias<<<SQ * DD / 256, 256, 0, stream>>>(x, b2);
        } else {
            attn0_kernel<<<NHD, 256, 0, stream>>>(q, k, v, x);
            // LN2 of row 0 only; also zero y1row for gemv accumulation
            ln_kernel<<<1, 256, 0, stream>>>(x, ln2_g + DD, ln2_b + DD, h2row, y1row, MLPD);
            gemv1_kernel<<<dim3(MLPD / 256, 32), 256, 0, stream>>>(h2row, w1 + (size_t)DD * MLPD, y1row);
            gelu_bias_kernel<<<MLPD / 256, 256, 0, stream>>>(y1row, b1 + MLPD);
            gemv2_kernel<<<dim3(DD / 256, 32), 256, 0, stream>>>(y1row, w2 + (size_t)DD * MLPD, x);
            head_kernel<<<1, 256, 0, stream>>>(x, b2 + DD, head_w, head_b, memory, out);
        }
    }
}